// Round 2
// baseline (369.931 us; speedup 1.0000x reference)
//
#include <hip/hip_runtime.h>
#include <math.h>

// B=512, T=256, C=384, H=64. One block = one batch.
// R5: 1024 thr = 16 waves (4/SIMD). R4 (8 waves) cut 188->131us with all
// counters scaling ~proportionally (Occ 10->21.6, Mfma 14.5->21.4) ->
// still latency-bound; LDS (148KB) pins 1 block/CU so more waves must come
// from a bigger block. Each wave owns ONE 16-row q-tile; causal balance via
// round-robin wave->SIMD: SIMD s hosts waves {s,s+4,s+8,s+12} with
// {1,2,3,4} flash iters = 10 each.
// Numerics unchanged: 3-term bf16 hi/lo split for x,W,q,k; single bf16 P,V.
#define B_ 512
#define T_ 256
#define C_ 384
#define H_ 64

typedef __attribute__((ext_vector_type(8))) short bf16x8;
typedef __attribute__((ext_vector_type(4))) float f32x4;

#define MFMA16(a, b, c) __builtin_amdgcn_mfma_f32_16x16x32_bf16((a), (b), (c), 0, 0, 0)

// ---- LDS map (bytes), total 148480 <= 163840. Row strides padded (+8 elem)
// so dword stride has gcd(.,32)<=4 -> <=2-way conflicts; frag reads 16B-aligned.
#define SM_KHI   0u        // khi[256][72] bf16 (row key, col h)
#define SM_KLO   36864u    // klo[256][72]
#define SM_VT    73728u    // vT[64][264] bf16 (row h, col key)
#define SM_WQH   73728u    // W-chunk staging WT[64][40], aliased under vT
#define SM_WQL   78848u
#define SM_WKH   83968u
#define SM_WKL   89088u
#define SM_WVH   94208u
#define SM_WVL   99328u
#define SM_XREG  107520u   // x-chunk staging; later q-slots; later P-slots
#define SM_XH    107520u   // xh[256][40] bf16
#define SM_XL    128000u   // xl[256][40]
#define SM_QS(s) (SM_XREG + (unsigned)(s)*4608u)  // qh[16][72] + ql[16][72]
#define SM_PS(w) (SM_XREG + (unsigned)(w)*2304u)  // p[16][72] per wave
#define SM_BYTES 148480u

static __device__ __forceinline__ unsigned short bhi(float x) {
    return (unsigned short)(__float_as_uint(x) >> 16);            // truncate
}
static __device__ __forceinline__ unsigned short blo(float x) {
    float h = __uint_as_float((__float_as_uint(x) >> 16) << 16);
    return (unsigned short)(__float_as_uint(x - h) >> 16);        // residual
}
static __device__ __forceinline__ unsigned short brne(float x) { // round-NE
    unsigned u = __float_as_uint(x);
    return (unsigned short)((u + 0x7FFFu + ((u >> 16) & 1u)) >> 16);
}
static __device__ __forceinline__ unsigned pk_hi(float a, float b) {
    return (unsigned)bhi(a) | ((unsigned)bhi(b) << 16);
}
static __device__ __forceinline__ unsigned pk_lo(float a, float b) {
    return (unsigned)blo(a) | ((unsigned)blo(b) << 16);
}

__global__ __launch_bounds__(1024, 4)
void head_mfma(const float* __restrict__ x,
               const float* __restrict__ Wq,
               const float* __restrict__ Wk,
               const float* __restrict__ Wv,
               float* __restrict__ out)
{
    __shared__ __align__(16) unsigned char sm[SM_BYTES];

    const int tid  = threadIdx.x;
    const int b    = blockIdx.x;
    const int w    = tid >> 6;        // wave 0..15, owns q-rows [16w,16w+16)
    const int lane = tid & 63;
    const int l15  = lane & 15;
    const int quad = lane >> 4;
    const int rA   = w * 16;

    // ================= Phase 1: q,k,v projections via MFMA =================
    f32x4 qac[4], kac[4], vac[4];
    #pragma unroll
    for (int nt = 0; nt < 4; ++nt) {
        f32x4 z = {0.f, 0.f, 0.f, 0.f};
        qac[nt] = z; kac[nt] = z; vac[nt] = z;
    }

    const int xrowi = tid >> 2;           // staged x row 0..255
    const int xq    = tid & 3;            // which 8-float slice of the chunk
    const float* xrow = x + ((size_t)b * T_ + xrowi) * C_ + xq * 8;
    const int hW = tid >> 4;              // W staging: h index 0..63
    const int cg = tid & 15;              // c-pair (2 c each)

    float4 xb[2];
    float  wbq[2], wbk[2], wbv[2];
    {   // prefetch chunk 0
        const float4* xp = (const float4*)(xrow);
        xb[0] = xp[0]; xb[1] = xp[1];
        const float* q0 = Wq + (size_t)(cg * 2) * H_ + hW;
        const float* k0 = Wk + (size_t)(cg * 2) * H_ + hW;
        const float* v0 = Wv + (size_t)(cg * 2) * H_ + hW;
        #pragma unroll
        for (int j = 0; j < 2; ++j) { wbq[j] = q0[j*H_]; wbk[j] = k0[j*H_]; wbv[j] = v0[j*H_]; }
    }

    #pragma unroll 1
    for (int cc = 0; cc < 12; ++cc) {
        // ---- stage x chunk: xh/xl[row][0..31], stride 40 elem (80 B)
        #pragma unroll
        for (int j = 0; j < 2; ++j) {
            uint2 hh, ll;
            hh.x = pk_hi(xb[j].x, xb[j].y); hh.y = pk_hi(xb[j].z, xb[j].w);
            ll.x = pk_lo(xb[j].x, xb[j].y); ll.y = pk_lo(xb[j].z, xb[j].w);
            *(uint2*)&sm[SM_XH + (unsigned)(xrowi*80 + xq*16 + j*8)] = hh;
            *(uint2*)&sm[SM_XL + (unsigned)(xrowi*80 + xq*16 + j*8)] = ll;
        }
        // ---- stage W chunks transposed: WT[h][c'], stride 40 elem
        {
            const unsigned wo = (unsigned)(hW*80 + cg*4);
            *(unsigned*)&sm[SM_WQH + wo] = pk_hi(wbq[0], wbq[1]);
            *(unsigned*)&sm[SM_WQL + wo] = pk_lo(wbq[0], wbq[1]);
            *(unsigned*)&sm[SM_WKH + wo] = pk_hi(wbk[0], wbk[1]);
            *(unsigned*)&sm[SM_WKL + wo] = pk_lo(wbk[0], wbk[1]);
            *(unsigned*)&sm[SM_WVH + wo] = pk_hi(wbv[0], wbv[1]);
            *(unsigned*)&sm[SM_WVL + wo] = pk_lo(wbv[0], wbv[1]);
        }
        __syncthreads();

        // ---- prefetch next chunk (overlaps MFMA below)
        if (cc < 11) {
            const float4* xp = (const float4*)(xrow + (cc + 1) * 32);
            xb[0] = xp[0]; xb[1] = xp[1];
            const size_t c0 = (size_t)((cc + 1) * 32 + cg * 2) * H_ + hW;
            #pragma unroll
            for (int j = 0; j < 2; ++j) {
                wbq[j] = Wq[c0 + (size_t)j*H_];
                wbk[j] = Wk[c0 + (size_t)j*H_];
                wbv[j] = Wv[c0 + (size_t)j*H_];
            }
        }

        // ---- A fragments for the wave's 16-row tile, hi & lo
        bf16x8 ah, al;
        {
            const unsigned ro = (unsigned)((rA + l15)*80 + quad*16);
            ah = *(const bf16x8*)&sm[SM_XH + ro];
            al = *(const bf16x8*)&sm[SM_XL + ro];
        }
        // ---- 3-term MFMA per matrix
#define PROJ_MAT(WTH, WTL, ACC)                                               \
        {                                                                     \
            bf16x8 bh[4], bl[4];                                              \
            _Pragma("unroll")                                                 \
            for (int nt = 0; nt < 4; ++nt) {                                  \
                const unsigned bo = (unsigned)((nt*16 + l15)*80 + quad*16);   \
                bh[nt] = *(const bf16x8*)&sm[(WTH) + bo];                     \
                bl[nt] = *(const bf16x8*)&sm[(WTL) + bo];                     \
            }                                                                 \
            _Pragma("unroll")                                                 \
            for (int nt = 0; nt < 4; ++nt) {                                  \
                f32x4 a = ACC[nt];                                            \
                a = MFMA16(al, bh[nt], a);                                    \
                a = MFMA16(ah, bl[nt], a);                                    \
                a = MFMA16(ah, bh[nt], a);                                    \
                ACC[nt] = a;                                                  \
            }                                                                 \
        }
        PROJ_MAT(SM_WQH, SM_WQL, qac)
        PROJ_MAT(SM_WKH, SM_WKL, kac)
        PROJ_MAT(SM_WVH, SM_WVL, vac)
        __syncthreads();   // staging consumed; next chunk may overwrite
    }

    // ====== Phase 1 epilogue: k -> khi/klo, v -> vT, q -> A-frags ==========
    constexpr float SCALE = 19.595917942265423f;   // sqrt(384) folded into q
    // C/D layout: row = quad*4 + reg (within 16-tile), col = l15.
    #pragma unroll
    for (int nt = 0; nt < 4; ++nt) {
        const f32x4 kv = kac[nt];
        const f32x4 vv = vac[nt];
        #pragma unroll
        for (int r = 0; r < 4; ++r) {
            const int row = rA + quad*4 + r;
            const int h   = nt*16 + l15;
            *(unsigned short*)&sm[SM_KHI + (unsigned)(row*144 + h*2)] = bhi(kv[r]);
            *(unsigned short*)&sm[SM_KLO + (unsigned)(row*144 + h*2)] = blo(kv[r]);
            *(unsigned short*)&sm[SM_VT  + (unsigned)(h*528 + row*2)] = brne(vv[r]);
        }
    }

    bf16x8 qAh[2], qAl[2];
    const int slot = w & 7;
    // two shifts through 8 q-transpose slots (aliased over x staging region)
#define Q_XPOSE()                                                             \
    {                                                                         \
        const unsigned qb = SM_QS(slot);                                      \
        _Pragma("unroll")                                                     \
        for (int nt = 0; nt < 4; ++nt) {                                      \
            const f32x4 qv = qac[nt];                                         \
            _Pragma("unroll")                                                 \
            for (int r = 0; r < 4; ++r) {                                     \
                const float qs = qv[r] * SCALE;                               \
                const int rl = quad*4 + r;                                    \
                const int h  = nt*16 + l15;                                   \
                *(unsigned short*)&sm[qb +         (unsigned)(rl*144 + h*2)] = bhi(qs); \
                *(unsigned short*)&sm[qb + 2304u + (unsigned)(rl*144 + h*2)] = blo(qs); \
            }                                                                 \
        }                                                                     \
        _Pragma("unroll")                                                     \
        for (int ks = 0; ks < 2; ++ks) {                                      \
            const unsigned qo = (unsigned)(l15*144 + ks*64 + quad*16);        \
            qAh[ks] = *(const bf16x8*)&sm[qb + qo];                           \
            qAl[ks] = *(const bf16x8*)&sm[qb + 2304u + qo];                   \
        }                                                                     \
    }
    if (w < 8) Q_XPOSE();
    __syncthreads();            // khi/klo/vT visible; slots free for waves 8..15
    if (w >= 8) Q_XPOSE();
    __syncthreads();            // q-slot area free -> becomes P slots

    // ================= Phase 2: flash attention, wave-local ================
    // Wave w: tile rows [16w,16w+16), kb = 0..(w>>2). Round-robin wave->SIMD
    // gives each SIMD waves {s,s+4,s+8,s+12} with {1,2,3,4} iters = balanced.
    f32x4 oac[4];
    float m_[4], l_[4];
    #pragma unroll
    for (int nt = 0; nt < 4; ++nt) { f32x4 z = {0.f,0.f,0.f,0.f}; oac[nt] = z; }
    #pragma unroll
    for (int r = 0; r < 4; ++r) { m_[r] = -1e30f; l_[r] = 0.f; }
    const unsigned pb = SM_PS(w);
    const int kbmax = w >> 2;

    #pragma unroll 1
    for (int kb = 0; kb <= kbmax; ++kb) {
        // ---- S = q k^T (3-term split), 16 rows x 64 keys
        bf16x8 kbh[4][2], kbl[4][2];
        #pragma unroll
        for (int nt = 0; nt < 4; ++nt)
            #pragma unroll
            for (int ks = 0; ks < 2; ++ks) {
                const unsigned ko = (unsigned)((kb*64 + nt*16 + l15)*144 + ks*64 + quad*16);
                kbh[nt][ks] = *(const bf16x8*)&sm[SM_KHI + ko];
                kbl[nt][ks] = *(const bf16x8*)&sm[SM_KLO + ko];
            }
        f32x4 sac[4];
        #pragma unroll
        for (int nt = 0; nt < 4; ++nt) {
            f32x4 a = {0.f,0.f,0.f,0.f};
            #pragma unroll
            for (int ks = 0; ks < 2; ++ks) {
                a = MFMA16(qAl[ks], kbh[nt][ks], a);
                a = MFMA16(qAh[ks], kbl[nt][ks], a);
                a = MFMA16(qAh[ks], kbh[nt][ks], a);
            }
            sac[nt] = a;
        }
        // ---- causal mask on diagonal block (last kb always holds diag)
        if (kb == kbmax) {
            #pragma unroll
            for (int nt = 0; nt < 4; ++nt)
                #pragma unroll
                for (int r = 0; r < 4; ++r) {
                    const int rg = rA + quad*4 + r;
                    const int kl = kb*64 + nt*16 + l15;
                    if (kl > rg) sac[nt][r] = -1e30f;
                }
        }
        // ---- online softmax (row stats per (quad,reg); cols in lanes)
        #pragma unroll
        for (int r = 0; r < 4; ++r) {
            float v = fmaxf(fmaxf(sac[0][r], sac[1][r]), fmaxf(sac[2][r], sac[3][r]));
            v = fmaxf(v, __shfl_xor(v, 1)); v = fmaxf(v, __shfl_xor(v, 2));
            v = fmaxf(v, __shfl_xor(v, 4)); v = fmaxf(v, __shfl_xor(v, 8));
            const float mnew  = fmaxf(m_[r], v);
            const float alpha = __expf(m_[r] - mnew);
            m_[r] = mnew;
            float rs = 0.f;
            #pragma unroll
            for (int nt = 0; nt < 4; ++nt) {
                const float p = __expf(sac[nt][r] - mnew);
                sac[nt][r] = p;
                rs += p;
            }
            rs += __shfl_xor(rs, 1); rs += __shfl_xor(rs, 2);
            rs += __shfl_xor(rs, 4); rs += __shfl_xor(rs, 8);
            l_[r] = l_[r] * alpha + rs;
            #pragma unroll
            for (int nt = 0; nt < 4; ++nt) oac[nt][r] *= alpha;
            // P -> bf16 in wave's P slot [16 rows][72 keys]
            const int rl = quad*4 + r;
            #pragma unroll
            for (int nt = 0; nt < 4; ++nt)
                *(unsigned short*)&sm[pb + (unsigned)(rl*144 + (nt*16 + l15)*2)] =
                    brne(sac[nt][r]);
        }
        // ---- O += P V  (P via A-frags from wave slot; V from vT)
        bf16x8 pA[2], vB[4][2];
        #pragma unroll
        for (int ks = 0; ks < 2; ++ks)
            pA[ks] = *(const bf16x8*)&sm[pb + (unsigned)(l15*144 + ks*64 + quad*16)];
        #pragma unroll
        for (int nt = 0; nt < 4; ++nt)
            #pragma unroll
            for (int ks = 0; ks < 2; ++ks)
                vB[nt][ks] = *(const bf16x8*)&sm[SM_VT + (unsigned)((nt*16 + l15)*528 + kb*128 + ks*64 + quad*16)];
        #pragma unroll
        for (int nt = 0; nt < 4; ++nt) {
            f32x4 a = oac[nt];
            a = MFMA16(pA[0], vB[nt][0], a);
            a = MFMA16(pA[1], vB[nt][1], a);
            oac[nt] = a;
        }
    }

    // ================= Epilogue: normalize + store =========================
    float* ob = out + (size_t)b * (T_ * H_);
    float inv[4];
    #pragma unroll
    for (int r = 0; r < 4; ++r) inv[r] = 1.0f / l_[r];
    #pragma unroll
    for (int nt = 0; nt < 4; ++nt)
        #pragma unroll
        for (int r = 0; r < 4; ++r) {
            const int row = rA + quad*4 + r;
            const int h   = nt*16 + l15;
            ob[row*64 + h] = oac[nt][r] * inv[r];
        }
}

extern "C" void kernel_launch(void* const* d_in, const int* in_sizes, int n_in,
                              void* d_out, int out_size, void* d_ws, size_t ws_size,
                              hipStream_t stream)
{
    const float* x  = (const float*)d_in[0];
    const float* Wq = (const float*)d_in[1];
    const float* Wk = (const float*)d_in[2];
    const float* Wv = (const float*)d_in[3];
    head_mfma<<<dim3(B_), dim3(1024), 0, stream>>>(x, Wq, Wk, Wv, (float*)d_out);
}

// Round 3
// 321.711 us; speedup vs baseline: 1.1499x; 1.1499x over previous
//
#include <hip/hip_runtime.h>
#include <math.h>

// B=512, T=256, C=384, H=64. One block = one batch, 512 thr = 8 waves (2/SIMD).
// R6: R4 structure (best, 131us) + (a) W hi/lo pre-packed ONCE into d_ws in the
// staged-transposed layout (kills 12 scalar gathers + ~60 pack VALU per thread
// per chunk, redundant across 512 blocks), (b) double-buffered phase-1 staging:
// 1 barrier/chunk, stage(c+1) overlaps MFMA(c).
// R5 lesson: 16 waves spilled (WRITE_SIZE +14MB) and doubled per-wave B-frag
// traffic -> regression. Stay at 8 waves.
// Numerics unchanged: 3-term bf16 hi/lo split for x,W,q,k; single bf16 P,V.
#define B_ 512
#define T_ 256
#define C_ 384
#define H_ 64

typedef __attribute__((ext_vector_type(8))) short bf16x8;
typedef __attribute__((ext_vector_type(4))) float f32x4;

#define MFMA16(a, b, c) __builtin_amdgcn_mfma_f32_16x16x32_bf16((a), (b), (c), 0, 0, 0)

// ---- LDS map (bytes), total 147456 <= 163840.
// Phase 1: two staging buffers buf[i] @ i*73728, each:
//   XH @+0 (xh[256][40] bf16, 80B rows), XL @+20480,
//   W  @+40960 (32768B: WQH,WQL,WKH,WKL,WVH,WVL @5120 each + 2048 pad).
// Phase 2 (aliased over the buffers, live only after phase 1):
//   KHI@0 khi[256][72], KLO@36864, VT@73728 vT[64][264],
//   QS(s)=107520+s*9216 (4 slots, two shifts), PS(w)=107520+w*2304.
#define BUFSZ    73728u
#define XH_OFF   0u
#define XL_OFF   20480u
#define W_OFF    40960u
#define SM_KHI   0u
#define SM_KLO   36864u
#define SM_VT    73728u
#define SM_QS(s) (107520u + (unsigned)(s)*9216u)
#define SM_PS(w) (107520u + (unsigned)(w)*2304u)
#define SM_BYTES 147456u
#define WCHUNK   32768u   // ws bytes per K-chunk (30720 live + pad)

static __device__ __forceinline__ unsigned short bhi(float x) {
    return (unsigned short)(__float_as_uint(x) >> 16);            // truncate
}
static __device__ __forceinline__ unsigned short blo(float x) {
    float h = __uint_as_float((__float_as_uint(x) >> 16) << 16);
    return (unsigned short)(__float_as_uint(x - h) >> 16);        // residual
}
static __device__ __forceinline__ unsigned short brne(float x) { // round-NE
    unsigned u = __float_as_uint(x);
    return (unsigned short)((u + 0x7FFFu + ((u >> 16) & 1u)) >> 16);
}
static __device__ __forceinline__ unsigned pk_hi(float a, float b) {
    return (unsigned)bhi(a) | ((unsigned)bhi(b) << 16);
}
static __device__ __forceinline__ unsigned pk_lo(float a, float b) {
    return (unsigned)blo(a) | ((unsigned)blo(b) << 16);
}

// ---- Pre-kernel: pack W -> ws in staged-transposed layout, once for all blocks.
// ws[cc*32768 + m*10240 + part*5120 + h*80 + c'*2] = {bhi,blo}(W_m[cc*32+c'][h])
__global__ __launch_bounds__(256)
void wprep(const float* __restrict__ Wq, const float* __restrict__ Wk,
           const float* __restrict__ Wv, unsigned char* __restrict__ ws)
{
    const int cc = blockIdx.x / 3, m = blockIdx.x % 3;
    const float* W = (m == 0) ? Wq : (m == 1) ? Wk : Wv;
    const int tid = threadIdx.x;           // 256 threads
    const int c   = tid >> 3;              // 0..31 (c within chunk)
    const int h0  = (tid & 7) * 8;         // 8 h per thread
    const float* src = W + (size_t)(cc * 32 + c) * H_ + h0;
    unsigned char* dst = ws + (size_t)cc * WCHUNK + (size_t)m * 10240u;
    #pragma unroll
    for (int j = 0; j < 8; ++j) {
        const float v = src[j];
        *(unsigned short*)(dst +         (unsigned)((h0 + j) * 80 + c * 2)) = bhi(v);
        *(unsigned short*)(dst + 5120u + (unsigned)((h0 + j) * 80 + c * 2)) = blo(v);
    }
}

__global__ __launch_bounds__(512, 2)
void head_mfma(const float* __restrict__ x,
               const unsigned char* __restrict__ wpack,
               float* __restrict__ out)
{
    __shared__ __align__(16) unsigned char sm[SM_BYTES];

    const int tid  = threadIdx.x;
    const int b    = blockIdx.x;
    const int w    = tid >> 6;        // wave 0..7
    const int lane = tid & 63;
    const int l15  = lane & 15;
    const int quad = lane >> 4;
    const int rA   = w * 16;          // tile A rows [rA, rA+16)
    const int rB   = 240 - w * 16;    // tile B rows [rB, rB+16)

    // ================= Phase 1: q,k,v projections via MFMA =================
    f32x4 qac[2][4], kac[2][4], vac[2][4];
    #pragma unroll
    for (int mt = 0; mt < 2; ++mt)
        #pragma unroll
        for (int nt = 0; nt < 4; ++nt) {
            f32x4 z = {0.f, 0.f, 0.f, 0.f};
            qac[mt][nt] = z; kac[mt][nt] = z; vac[mt][nt] = z;
        }

    const int xrowi = tid >> 1;           // staged x row 0..255
    const int xhalf = tid & 1;            // which 16-float half of the chunk
    const float* xrow = x + ((size_t)b * T_ + xrowi) * C_ + xhalf * 16;

    float4 xb[4];

#define X_PACK(BUF)                                                           \
    {                                                                         \
        _Pragma("unroll")                                                     \
        for (int j = 0; j < 4; ++j) {                                         \
            uint2 hh, ll;                                                     \
            hh.x = pk_hi(xb[j].x, xb[j].y); hh.y = pk_hi(xb[j].z, xb[j].w);   \
            ll.x = pk_lo(xb[j].x, xb[j].y); ll.y = pk_lo(xb[j].z, xb[j].w);   \
            *(uint2*)&sm[(BUF) + XH_OFF + (unsigned)(xrowi*80 + xhalf*32 + j*8)] = hh; \
            *(uint2*)&sm[(BUF) + XL_OFF + (unsigned)(xrowi*80 + xhalf*32 + j*8)] = ll; \
        }                                                                     \
    }

    // ---- prologue: stage chunk 0 into buf0, prefetch chunk 1 x
    {
        const float4* xp = (const float4*)xrow;
        #pragma unroll
        for (int j = 0; j < 4; ++j) xb[j] = xp[j];
        const uint4* wsrc = (const uint4*)(wpack);
        uint4 wt0 = wsrc[tid], wt1 = wsrc[512 + tid], wt2 = wsrc[1024 + tid], wt3 = wsrc[1536 + tid];
        X_PACK(0u)
        *(uint4*)&sm[W_OFF + (unsigned)tid * 16u]           = wt0;
        *(uint4*)&sm[W_OFF + (unsigned)(512  + tid) * 16u]  = wt1;
        *(uint4*)&sm[W_OFF + (unsigned)(1024 + tid) * 16u]  = wt2;
        *(uint4*)&sm[W_OFF + (unsigned)(1536 + tid) * 16u]  = wt3;
        const float4* xp1 = (const float4*)(xrow + 32);
        #pragma unroll
        for (int j = 0; j < 4; ++j) xb[j] = xp1[j];
    }
    __syncthreads();

    #pragma unroll 1
    for (int cc = 0; cc < 12; ++cc) {
        const unsigned bc = (unsigned)(cc & 1) * BUFSZ;   // compute buffer
        // ---- stage chunk cc+1 into the other buffer (overlaps MFMAs below)
        if (cc < 11) {
            const unsigned bn = BUFSZ - bc;
            const uint4* wsrc = (const uint4*)(wpack + (size_t)(cc + 1) * WCHUNK);
            uint4 wt0 = wsrc[tid], wt1 = wsrc[512 + tid], wt2 = wsrc[1024 + tid], wt3 = wsrc[1536 + tid];
            X_PACK(bn)
            *(uint4*)&sm[bn + W_OFF + (unsigned)tid * 16u]           = wt0;
            *(uint4*)&sm[bn + W_OFF + (unsigned)(512  + tid) * 16u]  = wt1;
            *(uint4*)&sm[bn + W_OFF + (unsigned)(1024 + tid) * 16u]  = wt2;
            *(uint4*)&sm[bn + W_OFF + (unsigned)(1536 + tid) * 16u]  = wt3;
            if (cc < 10) {   // prefetch x for chunk cc+2
                const float4* xp = (const float4*)(xrow + (cc + 2) * 32);
                #pragma unroll
                for (int j = 0; j < 4; ++j) xb[j] = xp[j];
            }
        }

        // ---- A fragments for the wave's two 16-row tiles, hi & lo
        bf16x8 ah[2], al[2];
        {
            const unsigned roA = (unsigned)((rA + l15)*80 + quad*16);
            const unsigned roB = (unsigned)((rB + l15)*80 + quad*16);
            ah[0] = *(const bf16x8*)&sm[bc + XH_OFF + roA];
            al[0] = *(const bf16x8*)&sm[bc + XL_OFF + roA];
            ah[1] = *(const bf16x8*)&sm[bc + XH_OFF + roB];
            al[1] = *(const bf16x8*)&sm[bc + XL_OFF + roB];
        }
        // ---- 3-term MFMA per matrix
#define PROJ_MAT(WTH, WTL, ACC)                                               \
        {                                                                     \
            bf16x8 bh[4], bl[4];                                              \
            _Pragma("unroll")                                                 \
            for (int nt = 0; nt < 4; ++nt) {                                  \
                const unsigned bo = (unsigned)((nt*16 + l15)*80 + quad*16);   \
                bh[nt] = *(const bf16x8*)&sm[(WTH) + bo];                     \
                bl[nt] = *(const bf16x8*)&sm[(WTL) + bo];                     \
            }                                                                 \
            _Pragma("unroll")                                                 \
            for (int mt = 0; mt < 2; ++mt)                                    \
                _Pragma("unroll")                                             \
                for (int nt = 0; nt < 4; ++nt) {                              \
                    f32x4 a = ACC[mt][nt];                                    \
                    a = MFMA16(al[mt], bh[nt], a);                            \
                    a = MFMA16(ah[mt], bl[nt], a);                            \
                    a = MFMA16(ah[mt], bh[nt], a);                            \
                    ACC[mt][nt] = a;                                          \
                }                                                             \
        }
        PROJ_MAT(bc + W_OFF +     0u, bc + W_OFF +  5120u, qac)
        PROJ_MAT(bc + W_OFF + 10240u, bc + W_OFF + 15360u, kac)
        PROJ_MAT(bc + W_OFF + 20480u, bc + W_OFF + 25600u, vac)
        __syncthreads();   // chunk cc consumed; next chunk staged
    }

    // ====== Phase 1 epilogue: k -> khi/klo, v -> vT, q -> A-frags ==========
    constexpr float SCALE = 19.595917942265423f;   // sqrt(384) folded into q
    // C/D layout: row = quad*4 + reg (within 16-tile), col = l15.
    #pragma unroll
    for (int mt = 0; mt < 2; ++mt) {
        const int r0m = mt ? rB : rA;
        #pragma unroll
        for (int nt = 0; nt < 4; ++nt) {
            const f32x4 kv = kac[mt][nt];
            const f32x4 vv = vac[mt][nt];
            #pragma unroll
            for (int r = 0; r < 4; ++r) {
                const int row = r0m + quad*4 + r;
                const int h   = nt*16 + l15;
                *(unsigned short*)&sm[SM_KHI + (unsigned)(row*144 + h*2)] = bhi(kv[r]);
                *(unsigned short*)&sm[SM_KLO + (unsigned)(row*144 + h*2)] = blo(kv[r]);
                *(unsigned short*)&sm[SM_VT  + (unsigned)(h*528 + row*2)] = brne(vv[r]);
            }
        }
    }

    bf16x8 qAh[2][2], qAl[2][2];
    const int slot = w & 3;
    // two shifts through 4 q-transpose slots (aliased over staging region)
#define Q_XPOSE()                                                             \
    {                                                                         \
        const unsigned qb = SM_QS(slot);                                      \
        _Pragma("unroll")                                                     \
        for (int mt = 0; mt < 2; ++mt)                                        \
            _Pragma("unroll")                                                 \
            for (int nt = 0; nt < 4; ++nt) {                                  \
                const f32x4 qv = qac[mt][nt];                                 \
                _Pragma("unroll")                                             \
                for (int r = 0; r < 4; ++r) {                                 \
                    const float qs = qv[r] * SCALE;                           \
                    const int rl = mt*16 + quad*4 + r;                        \
                    const int h  = nt*16 + l15;                               \
                    *(unsigned short*)&sm[qb +         (unsigned)(rl*144 + h*2)] = bhi(qs); \
                    *(unsigned short*)&sm[qb + 4608u + (unsigned)(rl*144 + h*2)] = blo(qs); \
                }                                                             \
            }                                                                 \
        _Pragma("unroll")                                                     \
        for (int mt = 0; mt < 2; ++mt)                                        \
            _Pragma("unroll")                                                 \
            for (int ks = 0; ks < 2; ++ks) {                                  \
                const unsigned qo = (unsigned)((mt*16 + l15)*144 + ks*64 + quad*16); \
                qAh[mt][ks] = *(const bf16x8*)&sm[qb + qo];                   \
                qAl[mt][ks] = *(const bf16x8*)&sm[qb + 4608u + qo];           \
            }                                                                 \
    }
    if (w < 4) Q_XPOSE();
    __syncthreads();            // khi/klo/vT visible; slots free for waves 4..7
    if (w >= 4) Q_XPOSE();
    __syncthreads();            // q-slot area free -> becomes P slots

    // ================= Phase 2: flash attention, wave-local ================
    // Tile pairing (w, 15-w): iters = (w>>2)+1 + ((15-w)>>2)+1 == 5 for all w.
    f32x4 oac[2][4];
    float m_[2][4], l_[2][4];
    #pragma unroll
    for (int mt = 0; mt < 2; ++mt) {
        #pragma unroll
        for (int nt = 0; nt < 4; ++nt) { f32x4 z = {0.f,0.f,0.f,0.f}; oac[mt][nt] = z; }
        #pragma unroll
        for (int r = 0; r < 4; ++r) { m_[mt][r] = -1e30f; l_[mt][r] = 0.f; }
    }
    const unsigned pb = SM_PS(w);

    #pragma unroll
    for (int tile = 0; tile < 2; ++tile) {
        const int r0    = tile ? rB : rA;
        const int kbmax = tile ? ((15 - w) >> 2) : (w >> 2);
        #pragma unroll 1
        for (int kb = 0; kb <= kbmax; ++kb) {
            // ---- S = q k^T (3-term split), 16 rows x 64 keys
            bf16x8 kbh[4][2], kbl[4][2];
            #pragma unroll
            for (int nt = 0; nt < 4; ++nt)
                #pragma unroll
                for (int ks = 0; ks < 2; ++ks) {
                    const unsigned ko = (unsigned)((kb*64 + nt*16 + l15)*144 + ks*64 + quad*16);
                    kbh[nt][ks] = *(const bf16x8*)&sm[SM_KHI + ko];
                    kbl[nt][ks] = *(const bf16x8*)&sm[SM_KLO + ko];
                }
            f32x4 sac[4];
            #pragma unroll
            for (int nt = 0; nt < 4; ++nt) {
                f32x4 a = {0.f,0.f,0.f,0.f};
                #pragma unroll
                for (int ks = 0; ks < 2; ++ks) {
                    a = MFMA16(qAl[tile][ks], kbh[nt][ks], a);
                    a = MFMA16(qAh[tile][ks], kbl[nt][ks], a);
                    a = MFMA16(qAh[tile][ks], kbh[nt][ks], a);
                }
                sac[nt] = a;
            }
            // ---- causal mask on diagonal block (last kb always holds diag)
            if (kb == kbmax) {
                #pragma unroll
                for (int nt = 0; nt < 4; ++nt)
                    #pragma unroll
                    for (int r = 0; r < 4; ++r) {
                        const int rg = r0 + quad*4 + r;
                        const int kl = kb*64 + nt*16 + l15;
                        if (kl > rg) sac[nt][r] = -1e30f;
                    }
            }
            // ---- online softmax (row stats per (quad,reg); cols in lanes)
            #pragma unroll
            for (int r = 0; r < 4; ++r) {
                float v = fmaxf(fmaxf(sac[0][r], sac[1][r]), fmaxf(sac[2][r], sac[3][r]));
                v = fmaxf(v, __shfl_xor(v, 1)); v = fmaxf(v, __shfl_xor(v, 2));
                v = fmaxf(v, __shfl_xor(v, 4)); v = fmaxf(v, __shfl_xor(v, 8));
                const float mnew  = fmaxf(m_[tile][r], v);
                const float alpha = __expf(m_[tile][r] - mnew);
                m_[tile][r] = mnew;
                float rs = 0.f;
                #pragma unroll
                for (int nt = 0; nt < 4; ++nt) {
                    const float p = __expf(sac[nt][r] - mnew);
                    sac[nt][r] = p;
                    rs += p;
                }
                rs += __shfl_xor(rs, 1); rs += __shfl_xor(rs, 2);
                rs += __shfl_xor(rs, 4); rs += __shfl_xor(rs, 8);
                l_[tile][r] = l_[tile][r] * alpha + rs;
                #pragma unroll
                for (int nt = 0; nt < 4; ++nt) oac[tile][nt][r] *= alpha;
                // P -> bf16 in wave's P slot [16 rows][72 keys]
                const int rl = quad*4 + r;
                #pragma unroll
                for (int nt = 0; nt < 4; ++nt)
                    *(unsigned short*)&sm[pb + (unsigned)(rl*144 + (nt*16 + l15)*2)] =
                        brne(sac[nt][r]);
            }
            // ---- O += P V  (P via A-frags from wave slot; V from vT)
            bf16x8 pA[2], vB[4][2];
            #pragma unroll
            for (int ks = 0; ks < 2; ++ks)
                pA[ks] = *(const bf16x8*)&sm[pb + (unsigned)(l15*144 + ks*64 + quad*16)];
            #pragma unroll
            for (int nt = 0; nt < 4; ++nt)
                #pragma unroll
                for (int ks = 0; ks < 2; ++ks)
                    vB[nt][ks] = *(const bf16x8*)&sm[SM_VT + (unsigned)((nt*16 + l15)*528 + kb*128 + ks*64 + quad*16)];
            #pragma unroll
            for (int nt = 0; nt < 4; ++nt) {
                f32x4 a = oac[tile][nt];
                a = MFMA16(pA[0], vB[nt][0], a);
                a = MFMA16(pA[1], vB[nt][1], a);
                oac[tile][nt] = a;
            }
        }
    }

    // ================= Epilogue: normalize + store =========================
    float* ob = out + (size_t)b * (T_ * H_);
    #pragma unroll
    for (int mt = 0; mt < 2; ++mt) {
        const int r0m = mt ? rB : rA;
        float inv[4];
        #pragma unroll
        for (int r = 0; r < 4; ++r) inv[r] = 1.0f / l_[mt][r];
        #pragma unroll
        for (int nt = 0; nt < 4; ++nt)
            #pragma unroll
            for (int r = 0; r < 4; ++r) {
                const int row = r0m + quad*4 + r;
                const int h   = nt*16 + l15;
                ob[row*64 + h] = oac[mt][nt][r] * inv[r];
            }
    }
}

extern "C" void kernel_launch(void* const* d_in, const int* in_sizes, int n_in,
                              void* d_out, int out_size, void* d_ws, size_t ws_size,
                              hipStream_t stream)
{
    const float* x  = (const float*)d_in[0];
    const float* Wq = (const float*)d_in[1];
    const float* Wk = (const float*)d_in[2];
    const float* Wv = (const float*)d_in[3];
    // Pre-pack W (hi/lo bf16, staged-transposed) into workspace: 12*32768 = 384KB.
    wprep<<<dim3(36), dim3(256), 0, stream>>>(Wq, Wk, Wv, (unsigned char*)d_ws);
    head_mfma<<<dim3(B_), dim3(512), 0, stream>>>(x, (const unsigned char*)d_ws,
                                                  (float*)d_out);
}